// Round 1
// baseline (1105.002 us; speedup 1.0000x reference)
//
#include <hip/hip_runtime.h>
#include <math.h>

#define N_ROWS   512     // 8*16*4
#define WINDOW   512
#define NBINS    257
#define N_COEFFS 771
#define STEP     256
#define N_FRAMES 128
#define N_SAMP   32768
#define CPB      16      // output chunks per synth block

// -------------------- Kernel 1: coeff GEMM + per-bin params --------------------
// pa[row*257+k] = {lm, phase, cos(phase), sin(phase)}
// pb[row*257+k] = {start*w_k, mag}
__global__ __launch_bounds__(256) void k_params(const float* __restrict__ sel,
                                                const float* __restrict__ items,
                                                float4* __restrict__ pa,
                                                float2* __restrict__ pb) {
    int row = blockIdx.x;
    int tid = threadIdx.x;
    __shared__ float s[512];
    float v0 = sel[row * 512 + tid];
    float v1 = sel[row * 512 + tid + 256];
    s[tid]       = v0 > 0.f ? v0 : 0.f;
    s[tid + 256] = v1 > 0.f ? v1 : 0.f;
    __syncthreads();
    for (int k = tid; k < NBINS; k += 256) {
        float cm = 0.f, cp = 0.f, cs = 0.f;
        #pragma unroll 8
        for (int i = 0; i < 512; ++i) {
            float sv = s[i];
            const float* ip = items + i * N_COEFFS + k;
            cm = fmaf(sv, ip[0],   cm);
            cp = fmaf(sv, ip[257], cp);
            cs = fmaf(sv, ip[514], cs);
        }
        float sig_m = 1.f / (1.f + expf(-cm));
        float mag   = 0.5f + sig_m * 0.9999f * 0.5f;   // BASE_RES + sig*0.9999*SPAN
        float lm    = logf(mag + 1e-12f);
        float ph    = tanhf(cp) * 3.14159265358979323846f;
        float sph, cph;
        sincosf(ph, &sph, &cph);
        float st = 1.f / (1.f + expf(-cs));
        float w  = (k == 0 || k == 256) ? (1.f / 512.f) : (2.f / 512.f);
        int idx = row * NBINS + k;
        pa[idx] = make_float4(lm, ph, cph, sph);
        pb[idx] = make_float2(st * w, mag);
    }
}

// -------------------- Kernel 2: synth (irfft + hann + OLA), unnormalized --------------------
__global__ __launch_bounds__(256) void k_synth(const float4* __restrict__ pa,
                                               const float2* __restrict__ pb,
                                               float* __restrict__ out,
                                               float* __restrict__ norms) {
    int row = blockIdx.x;      // 512
    int cb  = blockIdx.y;      // 8
    int tid = threadIdx.x;
    int c0  = cb * CPB;
    __shared__ float2 sab[NBINS];

    // per-thread bin state (bin k = tid; thread 0 also carries bin 256)
    float4 A = pa[row * NBINS + tid];
    float2 B = pb[row * NBINS + tid];
    float4 A2 = make_float4(0.f, 0.f, 1.f, 0.f);
    float2 B2 = make_float2(0.f, 0.f);
    if (tid == 0) { A2 = pa[row * NBINS + 256]; B2 = pb[row * NBINS + 256]; }

    int   fstart = (c0 == 0) ? 0 : (c0 - 1);
    float t0     = (float)(fstart + 1);

    float D = B.x * expf(A.x * t0);
    float st_, ct_;
    sincosf(A.y * t0, &st_, &ct_);
    float D2 = 0.f, st2 = 0.f, ct2 = 1.f;
    if (tid == 0) {
        D2 = B2.x * expf(A2.x * t0);
        sincosf(A2.y * t0, &st2, &ct2);
    }

    // per-thread DFT rotation constants for n = tid
    float sD, cD;
    sincosf(6.283185307179586f * (float)tid * (1.f / 512.f), &sD, &cD);
    // Hann: np.hanning(512) => 0.5 - 0.5*cos(2*pi*j/511)
    float h1 = 0.5f - 0.5f * cosf(6.283185307179586f * (float)tid / 511.f);
    float h2 = 0.5f - 0.5f * cosf(6.283185307179586f * (float)(tid + 256) / 511.f);

    float prevSecond = 0.f;
    float ssq = 0.f;
    int fend = c0 + CPB;

    for (int f = fstart; f < fend; ++f) {
        float a = D * ct_, b = D * st_;
        __syncthreads();   // previous frame's DFT reads done
        sab[tid] = make_float2(a, b);
        if (tid == 0) sab[256] = make_float2(D2 * ct2, D2 * st2);
        __syncthreads();

        // DFT for n = tid and n+256 via even/odd-k split
        float2 s0 = sab[0];
        float E = s0.x;    // k=0: cos=1, sin=0
        float O = 0.f;
        float cr = cD, sr = sD;   // theta for k=1
        #pragma unroll 4
        for (int kk = 1; kk <= 255; kk += 2) {
            float2 sA = sab[kk];
            O = fmaf(sA.x, cr, O);
            O = fmaf(-sA.y, sr, O);
            float nc = fmaf(cr, cD, -sr * sD);
            float ns = fmaf(sr, cD,  cr * sD);
            cr = nc; sr = ns;
            float2 sB = sab[kk + 1];
            E = fmaf(sB.x, cr, E);
            E = fmaf(-sB.y, sr, E);
            nc = fmaf(cr, cD, -sr * sD);
            ns = fmaf(sr, cD,  cr * sD);
            cr = nc; sr = ns;
        }
        float xn  = E + O;     // sample n
        float xn2 = E - O;     // sample n+256

        if (f >= c0) {
            float o = fmaf(xn, h1, prevSecond);
            out[row * N_SAMP + f * STEP + tid] = o;
            ssq = fmaf(o, o, ssq);
        }
        prevSecond = xn2 * h2;

        // advance recurrences: t -> t+1
        D *= B.y;
        float nct = fmaf(ct_, A.z, -st_ * A.w);
        float nst = fmaf(st_, A.z,  ct_ * A.w);
        ct_ = nct; st_ = nst;
        if (tid == 0) {
            D2 *= B2.y;
            float c2 = fmaf(ct2, A2.z, -st2 * A2.w);
            float s2 = fmaf(st2, A2.z,  ct2 * A2.w);
            ct2 = c2; st2 = s2;
        }
    }

    // reduce ssq -> norms[row]
    for (int off = 32; off > 0; off >>= 1) ssq += __shfl_down(ssq, off, 64);
    if ((tid & 63) == 0) atomicAdd(&norms[row], ssq);
}

// -------------------- Kernel 3: in-place normalize --------------------
__global__ __launch_bounds__(256) void k_norm(float* __restrict__ out,
                                              const float* __restrict__ norms) {
    int row = blockIdx.x;
    int tid = threadIdx.x;
    float scale = 1.f / (sqrtf(norms[row]) + 1e-8f);
    float4* p = (float4*)(out + row * N_SAMP);
    #pragma unroll 4
    for (int j = tid; j < N_SAMP / 4; j += 256) {
        float4 v = p[j];
        v.x *= scale; v.y *= scale; v.z *= scale; v.w *= scale;
        p[j] = v;
    }
}

extern "C" void kernel_launch(void* const* d_in, const int* in_sizes, int n_in,
                              void* d_out, int out_size, void* d_ws, size_t ws_size,
                              hipStream_t stream) {
    const float* sel   = (const float*)d_in[0];   // (8,16,4,512)
    const float* items = (const float*)d_in[1];   // (512,771)
    float* out = (float*)d_out;                   // (512, 32768)

    char* ws = (char*)d_ws;
    float*  norms = (float*)ws;                                   // 512 floats
    float4* pa    = (float4*)(ws + 2048);                         // 512*257 float4
    float2* pb    = (float2*)(ws + 2048 + (size_t)N_ROWS * NBINS * sizeof(float4));

    hipMemsetAsync(norms, 0, N_ROWS * sizeof(float), stream);
    k_params<<<dim3(N_ROWS), dim3(256), 0, stream>>>(sel, items, pa, pb);
    k_synth<<<dim3(N_ROWS, N_FRAMES / CPB), dim3(256), 0, stream>>>(pa, pb, out, norms);
    k_norm<<<dim3(N_ROWS), dim3(256), 0, stream>>>(out, norms);
}

// Round 2
// 344.892 us; speedup vs baseline: 3.2039x; 3.2039x over previous
//
#include <hip/hip_runtime.h>
#include <math.h>

#define N_ROWS   512     // 8*16*4
#define NBINS    257
#define N_COEFFS 771
#define STEP     256
#define N_FRAMES 128
#define N_SAMP   32768
#define KDIM     544     // 514 padded to 17*32
#define TWO_PI   6.283185307179586f

typedef _Float16 half8 __attribute__((ext_vector_type(8)));
typedef float floatx4 __attribute__((ext_vector_type(4)));

// -------------------- Kernel 1: coeff GEMM + per-bin params --------------------
// pa[row*257+k] = {lm, phase, cos(phase), sin(phase)}
// pb[row*257+k] = {start*w_k, mag}
__global__ __launch_bounds__(256) void k_params(const float* __restrict__ sel,
                                                const float* __restrict__ items,
                                                float4* __restrict__ pa,
                                                float2* __restrict__ pb) {
    int row = blockIdx.x;
    int tid = threadIdx.x;
    __shared__ float s[512];
    float v0 = sel[row * 512 + tid];
    float v1 = sel[row * 512 + tid + 256];
    s[tid]       = v0 > 0.f ? v0 : 0.f;
    s[tid + 256] = v1 > 0.f ? v1 : 0.f;
    __syncthreads();
    for (int k = tid; k < NBINS; k += 256) {
        float cm = 0.f, cp = 0.f, cs = 0.f;
        #pragma unroll 8
        for (int i = 0; i < 512; ++i) {
            float sv = s[i];
            const float* ip = items + i * N_COEFFS + k;
            cm = fmaf(sv, ip[0],   cm);
            cp = fmaf(sv, ip[257], cp);
            cs = fmaf(sv, ip[514], cs);
        }
        float sig_m = 1.f / (1.f + expf(-cm));
        float mag   = 0.5f + sig_m * 0.9999f * 0.5f;   // BASE_RES + sig*0.9999*SPAN
        float lm    = logf(mag + 1e-12f);
        float ph    = tanhf(cp) * 3.14159265358979323846f;
        float sph, cph;
        sincosf(ph, &sph, &cph);
        float st = 1.f / (1.f + expf(-cs));
        float w  = (k == 0 || k == 256) ? (1.f / 512.f) : (2.f / 512.f);
        int idx = row * NBINS + k;
        pa[idx] = make_float4(lm, ph, cph, sph);
        pb[idx] = make_float2(st * w, mag);
    }
}

// -------------------- Kernel 2: constant DFT basis, B^T layout (k-contiguous) ----
// Bt[n][k] = cos(2*pi*k*n/512) for k<257 ; -sin(2*pi*(k-257)*n/512) for 257<=k<514 ; 0 pad
__global__ __launch_bounds__(256) void k_basis(_Float16* __restrict__ Bt) {
    int n = blockIdx.x;
    int tid = threadIdx.x;
    for (int k = tid; k < KDIM; k += 256) {
        float v;
        if (k < NBINS) {
            int r = (k * n) & 511;                    // exact periodic reduction
            v = cosf(TWO_PI * (float)r * (1.f / 512.f));
        } else if (k < 2 * NBINS) {
            int kp = k - NBINS;
            int r = (kp * n) & 511;
            v = -sinf(TWO_PI * (float)r * (1.f / 512.f));
        } else {
            v = 0.f;
        }
        Bt[(size_t)n * KDIM + k] = (_Float16)v;
    }
}

// -------------------- Kernel 3: fill A (fp16, scaled by 512) --------------------
// A[row_local][f][k]     = 512*w*start*mag^(f+1)*cos(ph*(f+1))   (k<257)
// A[row_local][f][257+k] = 512*w*start*mag^(f+1)*sin(ph*(f+1))
__global__ __launch_bounds__(320) void k_afill(const float4* __restrict__ pa,
                                               const float2* __restrict__ pb,
                                               _Float16* __restrict__ A,
                                               int row0) {
    int row = row0 + blockIdx.x;
    int t = threadIdx.x;
    _Float16* Ar = A + (size_t)blockIdx.x * (N_FRAMES * KDIM);
    if (t < NBINS) {
        float4 P = pa[row * NBINS + t];
        float2 Q = pb[row * NBINS + t];
        float D = 512.f * Q.x * Q.y;      // t=1 amplitude
        float c = P.z, s = P.w;           // cos/sin(ph*1)
        for (int f = 0; f < N_FRAMES; ++f) {
            Ar[f * KDIM + t]         = (_Float16)(D * c);
            Ar[f * KDIM + NBINS + t] = (_Float16)(D * s);
            D *= Q.y;
            float nc = fmaf(c, P.z, -s * P.w);
            float ns = fmaf(s, P.z,  c * P.w);
            c = nc; s = ns;
        }
    } else if (t < NBINS + 30) {          // zero-pad k in [514,544)
        int k = 2 * NBINS + (t - NBINS);
        for (int f = 0; f < N_FRAMES; ++f) Ar[f * KDIM + k] = (_Float16)0.f;
    }
}

// -------------------- Kernel 4: MFMA GEMM + Hann + OLA (atomicAdd epilogue) -----
__global__ __launch_bounds__(256) void k_gemm(const _Float16* __restrict__ A,
                                              const _Float16* __restrict__ Bt,
                                              float* __restrict__ out,
                                              int row0) {
    int bx = blockIdx.x;          // local row
    int cb = blockIdx.y;          // column block (0..3) over 512 samples
    int t  = threadIdx.x;
    int lane = t & 63;
    int w    = t >> 6;
    int wm = w >> 1, wn = w & 1;  // 2x2 waves over 128x128 tile
    int quad = lane >> 4;
    int l16  = lane & 15;

    __shared__ _Float16 As[128 * 32];
    __shared__ _Float16 Bs[128 * 32];

    const _Float16* Ag = A  + (size_t)bx * (N_FRAMES * KDIM);
    const _Float16* Bg = Bt + (size_t)cb * 128 * KDIM;

    floatx4 acc[4][4] = {};

    int c0 = t, c1 = t + 256;
    int f0 = c0 >> 2, q0 = c0 & 3;
    int f1 = c1 >> 2, q1 = c1 & 3;

    for (int ks = 0; ks < KDIM / 32; ++ks) {
        int kb = ks * 32;
        __syncthreads();   // previous iteration's reads done
        *(half8*)&As[f0 * 32 + ((q0 ^ (f0 & 3)) * 8)] = *(const half8*)&Ag[f0 * KDIM + kb + q0 * 8];
        *(half8*)&As[f1 * 32 + ((q1 ^ (f1 & 3)) * 8)] = *(const half8*)&Ag[f1 * KDIM + kb + q1 * 8];
        *(half8*)&Bs[f0 * 32 + ((q0 ^ (f0 & 3)) * 8)] = *(const half8*)&Bg[f0 * KDIM + kb + q0 * 8];
        *(half8*)&Bs[f1 * 32 + ((q1 ^ (f1 & 3)) * 8)] = *(const half8*)&Bg[f1 * KDIM + kb + q1 * 8];
        __syncthreads();

        half8 av[4], bv[4];
        #pragma unroll
        for (int mt = 0; mt < 4; ++mt) {
            int m = wm * 64 + mt * 16 + l16;
            av[mt] = *(const half8*)&As[m * 32 + ((quad ^ (m & 3)) * 8)];
        }
        #pragma unroll
        for (int nt = 0; nt < 4; ++nt) {
            int u = wn * 64 + nt * 16 + l16;
            bv[nt] = *(const half8*)&Bs[u * 32 + ((quad ^ (u & 3)) * 8)];
        }
        #pragma unroll
        for (int mt = 0; mt < 4; ++mt) {
            #pragma unroll
            for (int nt = 0; nt < 4; ++nt) {
                acc[mt][nt] = __builtin_amdgcn_mfma_f32_16x16x32_f16(av[mt], bv[nt], acc[mt][nt], 0, 0, 0);
            }
        }
    }

    // Epilogue: val = frames[f][n]*hann[n]; first halves -> out[f*256+n],
    // second halves -> out[(f+1)*256 + n-256] (f=127 second half dropped).
    float* orow = out + (size_t)(row0 + bx) * N_SAMP;
    #pragma unroll
    for (int nt = 0; nt < 4; ++nt) {
        int n = cb * 128 + wn * 64 + nt * 16 + l16;
        float h = 0.5f - 0.5f * cosf(TWO_PI * (float)n / 511.f);
        #pragma unroll
        for (int mt = 0; mt < 4; ++mt) {
            int fb = wm * 64 + mt * 16 + quad * 4;
            #pragma unroll
            for (int r = 0; r < 4; ++r) {
                int f = fb + r;
                float val = acc[mt][nt][r] * h;
                if (n < 256) {
                    atomicAdd(orow + f * 256 + n, val);
                } else if (f < N_FRAMES - 1) {
                    atomicAdd(orow + (f + 1) * 256 + (n - 256), val);
                }
            }
        }
    }
}

// -------------------- Kernel 5: per-row sum of squares --------------------
__global__ __launch_bounds__(256) void k_sumsq(const float* __restrict__ out,
                                               float* __restrict__ norms) {
    int row = blockIdx.x;
    int t = threadIdx.x;
    const float4* p = (const float4*)(out + (size_t)row * N_SAMP);
    float ss = 0.f;
    #pragma unroll 4
    for (int j = t; j < N_SAMP / 4; j += 256) {
        float4 v = p[j];
        ss = fmaf(v.x, v.x, ss);
        ss = fmaf(v.y, v.y, ss);
        ss = fmaf(v.z, v.z, ss);
        ss = fmaf(v.w, v.w, ss);
    }
    for (int off = 32; off > 0; off >>= 1) ss += __shfl_down(ss, off, 64);
    __shared__ float red[4];
    if ((t & 63) == 0) red[t >> 6] = ss;
    __syncthreads();
    if (t == 0) norms[row] = red[0] + red[1] + red[2] + red[3];
}

// -------------------- Kernel 6: in-place scale --------------------
__global__ __launch_bounds__(256) void k_scale(float* __restrict__ out,
                                               const float* __restrict__ norms) {
    int row = blockIdx.x;
    int seg = blockIdx.y;
    int t = threadIdx.x;
    float scale = 1.f / (sqrtf(norms[row]) + 1e-8f);
    float4* p = (float4*)(out + (size_t)row * N_SAMP + seg * (N_SAMP / 4));
    #pragma unroll 4
    for (int j = t; j < N_SAMP / 16; j += 256) {
        float4 v = p[j];
        v.x *= scale; v.y *= scale; v.z *= scale; v.w *= scale;
        p[j] = v;
    }
}

extern "C" void kernel_launch(void* const* d_in, const int* in_sizes, int n_in,
                              void* d_out, int out_size, void* d_ws, size_t ws_size,
                              hipStream_t stream) {
    const float* sel   = (const float*)d_in[0];   // (8,16,4,512)
    const float* items = (const float*)d_in[1];   // (512,771)
    float* out = (float*)d_out;                   // (512, 32768)

    char* ws = (char*)d_ws;
    size_t off = 0;
    float* norms = (float*)(ws + off);  off += 512 * sizeof(float);           off = (off + 255) & ~255ull;
    float4* pa   = (float4*)(ws + off); off += (size_t)N_ROWS * NBINS * 16;   off = (off + 255) & ~255ull;
    float2* pb   = (float2*)(ws + off); off += (size_t)N_ROWS * NBINS * 8;    off = (off + 255) & ~255ull;
    _Float16* basis = (_Float16*)(ws + off); off += (size_t)512 * KDIM * 2;   off = (off + 255) & ~255ull;
    _Float16* Abuf  = (_Float16*)(ws + off); // 256*128*544*2 = 35.65 MB per group

    hipMemsetAsync(out, 0, (size_t)N_ROWS * N_SAMP * sizeof(float), stream);
    k_basis<<<dim3(512), dim3(256), 0, stream>>>(basis);
    k_params<<<dim3(N_ROWS), dim3(256), 0, stream>>>(sel, items, pa, pb);

    for (int g = 0; g < 2; ++g) {
        int row0 = g * 256;
        k_afill<<<dim3(256), dim3(320), 0, stream>>>(pa, pb, Abuf, row0);
        k_gemm<<<dim3(256, 4), dim3(256), 0, stream>>>(Abuf, basis, out, row0);
    }

    k_sumsq<<<dim3(N_ROWS), dim3(256), 0, stream>>>(out, norms);
    k_scale<<<dim3(N_ROWS, 4), dim3(256), 0, stream>>>(out, norms);
}

// Round 3
// 242.563 us; speedup vs baseline: 4.5555x; 1.4219x over previous
//
#include <hip/hip_runtime.h>
#include <math.h>

#define N_ROWS   512     // 8*16*4
#define NBINS    257
#define N_COEFFS 771
#define STEP     256
#define N_FRAMES 128
#define N_SAMP   32768
#define KDIM     544     // 514 padded to 17*32
#define TWO_PI   6.283185307179586f
#define TSTRIDE  132     // padded LDS stride for OLA tile

typedef _Float16 half8 __attribute__((ext_vector_type(8)));
typedef float floatx4 __attribute__((ext_vector_type(4)));

// -------------------- Kernel 1: coeff GEMM + per-bin params --------------------
// pa[row*257+k] = {lm, phase, cos(phase), sin(phase)}
// pb[row*257+k] = {start*w_k, mag}
__global__ __launch_bounds__(256) void k_params(const float* __restrict__ sel,
                                                const float* __restrict__ items,
                                                float4* __restrict__ pa,
                                                float2* __restrict__ pb) {
    int row = blockIdx.x;
    int tid = threadIdx.x;
    __shared__ float s[512];
    float v0 = sel[row * 512 + tid];
    float v1 = sel[row * 512 + tid + 256];
    s[tid]       = v0 > 0.f ? v0 : 0.f;
    s[tid + 256] = v1 > 0.f ? v1 : 0.f;
    __syncthreads();
    for (int k = tid; k < NBINS; k += 256) {
        float cm = 0.f, cp = 0.f, cs = 0.f;
        #pragma unroll 8
        for (int i = 0; i < 512; ++i) {
            float sv = s[i];
            const float* ip = items + i * N_COEFFS + k;
            cm = fmaf(sv, ip[0],   cm);
            cp = fmaf(sv, ip[257], cp);
            cs = fmaf(sv, ip[514], cs);
        }
        float sig_m = 1.f / (1.f + expf(-cm));
        float mag   = 0.5f + sig_m * 0.9999f * 0.5f;   // BASE_RES + sig*0.9999*SPAN
        float lm    = logf(mag + 1e-12f);
        float ph    = tanhf(cp) * 3.14159265358979323846f;
        float sph, cph;
        sincosf(ph, &sph, &cph);
        float st = 1.f / (1.f + expf(-cs));
        float w  = (k == 0 || k == 256) ? (1.f / 512.f) : (2.f / 512.f);
        int idx = row * NBINS + k;
        pa[idx] = make_float4(lm, ph, cph, sph);
        pb[idx] = make_float2(st * w, mag);
    }
}

// -------------------- Kernel 2: constant DFT basis, PERMUTED columns ------------
// Block jg (0..511) is permuted column jg; actual sample index:
//   n = (jg>>7)*64 + (jg&63) + ((jg>>6)&1)*256
// so block cb of k_gemm (columns cb*128..cb*128+127) owns samples
// {cb*64..cb*64+63} (first halves) and {256+cb*64..256+cb*64+63} (second halves).
// Bt[jg][k] = cos(2*pi*k*n/512) (k<257) ; -sin(...) (257<=k<514) ; 0 pad
__global__ __launch_bounds__(256) void k_basis(_Float16* __restrict__ Bt) {
    int jg = blockIdx.x;
    int n  = ((jg >> 7) << 6) + (jg & 63) + (((jg >> 6) & 1) << 8);
    int tid = threadIdx.x;
    for (int k = tid; k < KDIM; k += 256) {
        float v;
        if (k < NBINS) {
            int r = (k * n) & 511;                    // exact periodic reduction
            v = cosf(TWO_PI * (float)r * (1.f / 512.f));
        } else if (k < 2 * NBINS) {
            int kp = k - NBINS;
            int r = (kp * n) & 511;
            v = -sinf(TWO_PI * (float)r * (1.f / 512.f));
        } else {
            v = 0.f;
        }
        Bt[(size_t)jg * KDIM + k] = (_Float16)v;
    }
}

// -------------------- Kernel 3: fill A (fp16, scaled by 512) --------------------
__global__ __launch_bounds__(320) void k_afill(const float4* __restrict__ pa,
                                               const float2* __restrict__ pb,
                                               _Float16* __restrict__ A,
                                               int row0) {
    int row = row0 + blockIdx.x;
    int t = threadIdx.x;
    _Float16* Ar = A + (size_t)blockIdx.x * (N_FRAMES * KDIM);
    if (t < NBINS) {
        float4 P = pa[row * NBINS + t];
        float2 Q = pb[row * NBINS + t];
        float D = 512.f * Q.x * Q.y;      // t=1 amplitude
        float c = P.z, s = P.w;           // cos/sin(ph*1)
        for (int f = 0; f < N_FRAMES; ++f) {
            Ar[f * KDIM + t]         = (_Float16)(D * c);
            Ar[f * KDIM + NBINS + t] = (_Float16)(D * s);
            D *= Q.y;
            float nc = fmaf(c, P.z, -s * P.w);
            float ns = fmaf(s, P.z,  c * P.w);
            c = nc; s = ns;
        }
    } else if (t < NBINS + 30) {          // zero-pad k in [514,544)
        int k = 2 * NBINS + (t - NBINS);
        for (int f = 0; f < N_FRAMES; ++f) Ar[f * KDIM + k] = (_Float16)0.f;
    }
}

// -------------------- Kernel 4: MFMA GEMM + Hann + OLA (atomic-free) ------------
__global__ __launch_bounds__(256) void k_gemm(const _Float16* __restrict__ A,
                                              const _Float16* __restrict__ Bt,
                                              float* __restrict__ out,
                                              float* __restrict__ norms,
                                              int row0) {
    int bx = blockIdx.x;          // local row
    int cb = blockIdx.y;          // column block (0..3)
    int t  = threadIdx.x;
    int lane = t & 63;
    int w    = t >> 6;
    int wm = w >> 1, wn = w & 1;  // 2x2 waves over 128x128 tile
    int quad = lane >> 4;
    int l16  = lane & 15;

    __shared__ __align__(16) char smem[67616];
    _Float16* As = (_Float16*)smem;            // 128*32 halves = 8 KB
    _Float16* Bs = (_Float16*)(smem + 8192);   // 8 KB
    float*    T  = (float*)smem;               // aliased after K-loop: 128 x TSTRIDE
    float*    red = (float*)(smem + 67584);    // 4 floats

    const _Float16* Ag = A  + (size_t)bx * (N_FRAMES * KDIM);
    const _Float16* Bg = Bt + (size_t)cb * 128 * KDIM;

    floatx4 acc[4][4] = {};

    int c0 = t, c1 = t + 256;
    int f0 = c0 >> 2, q0 = c0 & 3;
    int f1 = c1 >> 2, q1 = c1 & 3;

    for (int ks = 0; ks < KDIM / 32; ++ks) {
        int kb = ks * 32;
        __syncthreads();   // previous iteration's reads done
        *(half8*)&As[f0 * 32 + ((q0 ^ (f0 & 3)) * 8)] = *(const half8*)&Ag[f0 * KDIM + kb + q0 * 8];
        *(half8*)&As[f1 * 32 + ((q1 ^ (f1 & 3)) * 8)] = *(const half8*)&Ag[f1 * KDIM + kb + q1 * 8];
        *(half8*)&Bs[f0 * 32 + ((q0 ^ (f0 & 3)) * 8)] = *(const half8*)&Bg[f0 * KDIM + kb + q0 * 8];
        *(half8*)&Bs[f1 * 32 + ((q1 ^ (f1 & 3)) * 8)] = *(const half8*)&Bg[f1 * KDIM + kb + q1 * 8];
        __syncthreads();

        half8 av[4], bv[4];
        #pragma unroll
        for (int mt = 0; mt < 4; ++mt) {
            int m = wm * 64 + mt * 16 + l16;
            av[mt] = *(const half8*)&As[m * 32 + ((quad ^ (m & 3)) * 8)];
        }
        #pragma unroll
        for (int nt = 0; nt < 4; ++nt) {
            int u = wn * 64 + nt * 16 + l16;
            bv[nt] = *(const half8*)&Bs[u * 32 + ((quad ^ (u & 3)) * 8)];
        }
        #pragma unroll
        for (int mt = 0; mt < 4; ++mt) {
            #pragma unroll
            for (int nt = 0; nt < 4; ++nt) {
                acc[mt][nt] = __builtin_amdgcn_mfma_f32_16x16x32_f16(av[mt], bv[nt], acc[mt][nt], 0, 0, 0);
            }
        }
    }

    // ---- Epilogue: window, stage to LDS, OLA in-block, exclusive writes ----
    __syncthreads();   // all staging-LDS reads done before T overwrite
    #pragma unroll
    for (int nt = 0; nt < 4; ++nt) {
        int r = wn * 64 + nt * 16 + l16;             // permuted column 0..127
        int n = (cb << 6) + (r & 63) + ((r >> 6) << 8);  // actual sample 0..511
        float h = 0.5f - 0.5f * cosf(TWO_PI * (float)n / 511.f);
        #pragma unroll
        for (int mt = 0; mt < 4; ++mt) {
            int fb = wm * 64 + mt * 16 + quad * 4;
            #pragma unroll
            for (int rr = 0; rr < 4; ++rr) {
                T[(fb + rr) * TSTRIDE + r] = acc[mt][nt][rr] * h;
            }
        }
    }
    __syncthreads();

    // out[row, f*256 + cb*64 + rr] = T[f][rr] + T[f-1][rr+64]
    float* orow = out + (size_t)(row0 + bx) * N_SAMP + (cb << 6);
    int rr = t & 63, wv = t >> 6;
    float ssq = 0.f;
    #pragma unroll 4
    for (int it = 0; it < 32; ++it) {
        int f = it * 4 + wv;
        float v = T[f * TSTRIDE + rr];
        if (f > 0) v += T[(f - 1) * TSTRIDE + rr + 64];
        orow[f * 256 + rr] = v;
        ssq = fmaf(v, v, ssq);
    }
    for (int off = 32; off > 0; off >>= 1) ssq += __shfl_down(ssq, off, 64);
    __syncthreads();   // all T reads complete before red write (red is separate, but keep order)
    if ((t & 63) == 0) red[wv] = ssq;
    __syncthreads();
    if (t == 0) atomicAdd(&norms[row0 + bx], red[0] + red[1] + red[2] + red[3]);
}

// -------------------- Kernel 5: in-place scale --------------------
__global__ __launch_bounds__(256) void k_scale(float* __restrict__ out,
                                               const float* __restrict__ norms) {
    int row = blockIdx.x;
    int seg = blockIdx.y;
    int t = threadIdx.x;
    float scale = 1.f / (sqrtf(norms[row]) + 1e-8f);
    float4* p = (float4*)(out + (size_t)row * N_SAMP + seg * (N_SAMP / 4));
    #pragma unroll 4
    for (int j = t; j < N_SAMP / 16; j += 256) {
        float4 v = p[j];
        v.x *= scale; v.y *= scale; v.z *= scale; v.w *= scale;
        p[j] = v;
    }
}

extern "C" void kernel_launch(void* const* d_in, const int* in_sizes, int n_in,
                              void* d_out, int out_size, void* d_ws, size_t ws_size,
                              hipStream_t stream) {
    const float* sel   = (const float*)d_in[0];   // (8,16,4,512)
    const float* items = (const float*)d_in[1];   // (512,771)
    float* out = (float*)d_out;                   // (512, 32768)

    char* ws = (char*)d_ws;
    size_t off = 0;
    float* norms = (float*)(ws + off);  off += 512 * sizeof(float);           off = (off + 255) & ~255ull;
    float4* pa   = (float4*)(ws + off); off += (size_t)N_ROWS * NBINS * 16;   off = (off + 255) & ~255ull;
    float2* pb   = (float2*)(ws + off); off += (size_t)N_ROWS * NBINS * 8;    off = (off + 255) & ~255ull;
    _Float16* basis = (_Float16*)(ws + off); off += (size_t)512 * KDIM * 2;   off = (off + 255) & ~255ull;
    _Float16* Abuf  = (_Float16*)(ws + off);

    // One group (512 rows, 71.3 MB A-buffer) if ws allows, else two of 256.
    size_t needFull = (size_t)512 * N_FRAMES * KDIM * 2;
    int G = (ws_size - off >= needFull) ? 512 : 256;

    hipMemsetAsync(norms, 0, 512 * sizeof(float), stream);
    k_basis<<<dim3(512), dim3(256), 0, stream>>>(basis);
    k_params<<<dim3(N_ROWS), dim3(256), 0, stream>>>(sel, items, pa, pb);

    for (int g = 0; g < 512 / G; ++g) {
        int row0 = g * G;
        k_afill<<<dim3(G), dim3(320), 0, stream>>>(pa, pb, Abuf, row0);
        k_gemm<<<dim3(G, 4), dim3(256), 0, stream>>>(Abuf, basis, out, norms, row0);
    }

    k_scale<<<dim3(N_ROWS, 4), dim3(256), 0, stream>>>(out, norms);
}

// Round 4
// 189.605 us; speedup vs baseline: 5.8279x; 1.2793x over previous
//
#include <hip/hip_runtime.h>
#include <math.h>

#define N_ROWS   512     // 8*16*4
#define NBINS    257
#define N_COEFFS 771
#define STEP     256
#define N_FRAMES 128
#define N_SAMP   32768
#define KDIM     544     // 514 padded to 17*32
#define NCHUNK   17
#define TWO_PI   6.283185307179586f

typedef _Float16 half8 __attribute__((ext_vector_type(8)));
typedef float floatx4 __attribute__((ext_vector_type(4)));

// -------------------- Kernel 1: coeff GEMM + per-bin params (2 rows/block) -----
// pa[row*257+k] = {lm, phase, cos(phase), sin(phase)}
// pb[row*257+k] = {start*w_k, mag}
__global__ __launch_bounds__(320) void k_params(const float* __restrict__ sel,
                                                const float* __restrict__ items,
                                                float4* __restrict__ pa,
                                                float2* __restrict__ pb) {
    int rp  = blockIdx.x;          // row pair
    int t   = threadIdx.x;
    __shared__ float s[1024];
    for (int i = t; i < 1024; i += 320) {
        int rr = i >> 9, j = i & 511;
        float v = sel[(rp * 2 + rr) * 512 + j];
        s[i] = v > 0.f ? v : 0.f;
    }
    __syncthreads();
    if (t < NBINS) {
        int k = t;
        float cm0 = 0.f, cp0 = 0.f, cs0 = 0.f;
        float cm1 = 0.f, cp1 = 0.f, cs1 = 0.f;
        #pragma unroll 8
        for (int i = 0; i < 512; ++i) {
            const float* ip = items + i * N_COEFFS + k;
            float i0 = ip[0], i1 = ip[257], i2 = ip[514];
            float s0 = s[i], s1 = s[512 + i];
            cm0 = fmaf(s0, i0, cm0);  cm1 = fmaf(s1, i0, cm1);
            cp0 = fmaf(s0, i1, cp0);  cp1 = fmaf(s1, i1, cp1);
            cs0 = fmaf(s0, i2, cs0);  cs1 = fmaf(s1, i2, cs1);
        }
        float w = (k == 0 || k == 256) ? (1.f / 512.f) : (2.f / 512.f);
        #pragma unroll
        for (int rr = 0; rr < 2; ++rr) {
            float cm = rr ? cm1 : cm0, cp = rr ? cp1 : cp0, cs = rr ? cs1 : cs0;
            float sig_m = 1.f / (1.f + expf(-cm));
            float mag   = 0.5f + sig_m * 0.9999f * 0.5f;
            float lm    = logf(mag + 1e-12f);
            float ph    = tanhf(cp) * 3.14159265358979323846f;
            float sph, cph;
            sincosf(ph, &sph, &cph);
            float st = 1.f / (1.f + expf(-cs));
            int idx = (rp * 2 + rr) * NBINS + k;
            pa[idx] = make_float4(lm, ph, cph, sph);
            pb[idx] = make_float2(st * w, mag);
        }
    }
}

// -------------------- Kernel 2: constant DFT basis, PERMUTED columns ------------
// jg -> sample n = (jg>>7)*64 + (jg&63) + ((jg>>6)&1)*256
__global__ __launch_bounds__(256) void k_basis(_Float16* __restrict__ Bt) {
    int jg = blockIdx.x;
    int n  = ((jg >> 7) << 6) + (jg & 63) + (((jg >> 6) & 1) << 8);
    int tid = threadIdx.x;
    for (int k = tid; k < KDIM; k += 256) {
        float v;
        if (k < NBINS) {
            int r = (k * n) & 511;
            v = cosf(TWO_PI * (float)r * (1.f / 512.f));
        } else if (k < 2 * NBINS) {
            int kp = k - NBINS;
            int r = (kp * n) & 511;
            v = -sinf(TWO_PI * (float)r * (1.f / 512.f));
        } else {
            v = 0.f;
        }
        Bt[(size_t)jg * KDIM + k] = (_Float16)v;
    }
}

// -------------------- Kernel 3: fused A-gen(LDS) + MFMA + OLA + norm + scale ----
// One block per row, 512 threads (8 waves). A lives only in LDS.
__global__ __launch_bounds__(512, 2) void k_row(const float4* __restrict__ pa,
                                                const float2* __restrict__ pb,
                                                const _Float16* __restrict__ basis,
                                                float* __restrict__ out) {
    __shared__ _Float16 Asm[NCHUNK * 128 * 32];   // 139264 B, chunked+swizzled
    __shared__ _Float16 Bsm[2][128 * 32];         // 16384 B, double buffer
    __shared__ float    SBB[7][64];               // wave-boundary OLA exchange
    __shared__ float    red[8];

    const int row  = blockIdx.x;
    const int t    = threadIdx.x;
    const int lane = t & 63;
    const int w    = t >> 6;            // wave 0..7, owns frames [w*16, w*16+16)
    const int quad = lane >> 4;
    const int l16  = lane & 15;
    const int j    = t >> 2;            // staging row 0..127
    const int q    = t & 3;             // staging k-group

    // ---- prologue global B loads (latency hidden under A-gen) ----
    const size_t bstride = KDIM;
    half8 L0 = *(const half8*)(basis + (size_t)j * bstride + 0 * 32 + q * 8);
    half8 nxt = *(const half8*)(basis + (size_t)j * bstride + 1 * 32 + q * 8);

    // ---- zero pad chunk 16 (k 512..543; real k 512,513 overwritten below) ----
    {
        half8 z = {};
        *(half8*)&Asm[16 * 4096 + t * 8] = z;
    }
    __syncthreads();

    // ---- A generation into LDS (fp16, scaled by 512) ----
    if (t < NBINS) {
        float4 P = pa[row * NBINS + t];
        float2 Q = pb[row * NBINS + t];
        float D = 512.f * Q.x * Q.y;      // amplitude at frame t=1
        float c = P.z, s = P.w;           // cos/sin(ph*1)
        int k1 = t, k2 = NBINS + t;
        int c1 = k1 >> 5, g1 = (k1 & 31) >> 3, o1 = k1 & 7;
        int c2 = k2 >> 5, g2 = (k2 & 31) >> 3, o2 = k2 & 7;
        for (int f = 0; f < N_FRAMES; ++f) {
            int sw = f & 3;
            Asm[c1 * 4096 + f * 32 + ((g1 ^ sw) << 3) + o1] = (_Float16)(D * c);
            Asm[c2 * 4096 + f * 32 + ((g2 ^ sw) << 3) + o2] = (_Float16)(D * s);
            D *= Q.y;
            float nc = fmaf(c, P.z, -s * P.w);
            float ns = fmaf(s, P.z,  c * P.w);
            c = nc; s = ns;
        }
    }
    // stage B(it=0) into buf 0
    *(half8*)&Bsm[0][j * 32 + ((q ^ (j & 3)) << 3)] = L0;
    __syncthreads();

    // ---- main loop: cb outer (unrolled), ks inner; 1 barrier/iter ----
    int p = 0;
    int lcb = 0, lks = 2;                 // prefetch cursor (next-next iter)
    const int m = w * 16 + l16;           // A fragment row for this lane
    const int aswz = ((quad ^ (m & 3)) << 3);
    float oreg[4][4][4];                  // [cb][nt][rr] held outputs
    float ssq = 0.f;

    #pragma unroll
    for (int cb = 0; cb < 4; ++cb) {
        floatx4 acc[8] = {};
        for (int ks = 0; ks < NCHUNK; ++ks) {
            half8 cur = nxt;
            if (lcb < 4) {
                nxt = *(const half8*)(basis + (size_t)(lcb * 128 + j) * bstride + lks * 32 + q * 8);
                if (++lks == NCHUNK) { lks = 0; ++lcb; }
            }
            if (!(cb == 3 && ks == NCHUNK - 1)) {
                *(half8*)&Bsm[p ^ 1][j * 32 + ((q ^ (j & 3)) << 3)] = cur;
            }
            half8 av = *(const half8*)&Asm[ks * 4096 + m * 32 + aswz];
            #pragma unroll
            for (int nt = 0; nt < 8; ++nt) {
                int u = nt * 16 + l16;
                half8 bv = *(const half8*)&Bsm[p][u * 32 + ((quad ^ (u & 3)) << 3)];
                acc[nt] = __builtin_amdgcn_mfma_f32_16x16x32_f16(av, bv, acc[nt], 0, 0, 0);
            }
            __syncthreads();
            p ^= 1;
        }

        // ---- OLA epilogue for this cb: all in registers ----
        float W2r[4][4];
        #pragma unroll
        for (int nt = 0; nt < 4; ++nt) {
            int n2 = 256 + cb * 64 + nt * 16 + l16;
            float h2 = 0.5f - 0.5f * cosf(TWO_PI * (float)n2 / 511.f);
            #pragma unroll
            for (int rr = 0; rr < 4; ++rr) W2r[nt][rr] = acc[nt + 4][rr] * h2;
        }
        if (quad == 3 && w < 7) {
            #pragma unroll
            for (int nt = 0; nt < 4; ++nt) SBB[w][nt * 16 + l16] = W2r[nt][3];
        }
        __syncthreads();
        #pragma unroll
        for (int nt = 0; nt < 4; ++nt) {
            int r0 = nt * 16 + l16;
            int n1 = cb * 64 + r0;
            float h1 = 0.5f - 0.5f * cosf(TWO_PI * (float)n1 / 511.f);
            float prev3 = __shfl(W2r[nt][3], (lane + 48) & 63, 64); // from lane-16
            float sbv = SBB[w > 0 ? w - 1 : 0][r0];
            float sec0 = (quad > 0) ? prev3 : ((w > 0) ? sbv : 0.f);
            float v0 = fmaf(acc[nt][0], h1, sec0);
            oreg[cb][nt][0] = v0; ssq = fmaf(v0, v0, ssq);
            #pragma unroll
            for (int rr = 1; rr < 4; ++rr) {
                float v = fmaf(acc[nt][rr], h1, W2r[nt][rr - 1]);
                oreg[cb][nt][rr] = v; ssq = fmaf(v, v, ssq);
            }
        }
    }

    // ---- block reduction of sum-of-squares, scale, single write ----
    #pragma unroll
    for (int off = 32; off > 0; off >>= 1) ssq += __shfl_down(ssq, off, 64);
    if (lane == 0) red[w] = ssq;
    __syncthreads();
    float tot = red[0] + red[1] + red[2] + red[3] + red[4] + red[5] + red[6] + red[7];
    float scale = 1.f / (sqrtf(tot) + 1e-8f);

    float* orow = out + (size_t)row * N_SAMP;
    #pragma unroll
    for (int cb = 0; cb < 4; ++cb) {
        #pragma unroll
        for (int nt = 0; nt < 4; ++nt) {
            int c = cb * 64 + nt * 16 + l16;
            #pragma unroll
            for (int rr = 0; rr < 4; ++rr) {
                int f = w * 16 + quad * 4 + rr;
                orow[f * 256 + c] = oreg[cb][nt][rr] * scale;
            }
        }
    }
}

extern "C" void kernel_launch(void* const* d_in, const int* in_sizes, int n_in,
                              void* d_out, int out_size, void* d_ws, size_t ws_size,
                              hipStream_t stream) {
    const float* sel   = (const float*)d_in[0];   // (8,16,4,512)
    const float* items = (const float*)d_in[1];   // (512,771)
    float* out = (float*)d_out;                   // (512, 32768)

    char* ws = (char*)d_ws;
    size_t off = 0;
    float4* pa   = (float4*)(ws + off); off += (size_t)N_ROWS * NBINS * 16;   off = (off + 255) & ~255ull;
    float2* pb   = (float2*)(ws + off); off += (size_t)N_ROWS * NBINS * 8;    off = (off + 255) & ~255ull;
    _Float16* basis = (_Float16*)(ws + off);

    k_params<<<dim3(N_ROWS / 2), dim3(320), 0, stream>>>(sel, items, pa, pb);
    k_basis<<<dim3(512), dim3(256), 0, stream>>>(basis);
    k_row<<<dim3(N_ROWS), dim3(512), 0, stream>>>(pa, pb, basis, out);
}

// Round 5
// 182.487 us; speedup vs baseline: 6.0552x; 1.0390x over previous
//
#include <hip/hip_runtime.h>
#include <math.h>

#define N_ROWS   512     // 8*16*4
#define NBINS    257
#define N_COEFFS 771
#define STEP     256
#define N_FRAMES 128
#define N_SAMP   32768
#define KDIM     576     // 514 padded to 18*32
#define NCHUNK   18
#define PCH      9       // chunks per A-phase
#define PCOLS    288     // K-columns per A-phase
#define TWO_PI   6.283185307179586f

typedef _Float16 half8 __attribute__((ext_vector_type(8)));
typedef float floatx4 __attribute__((ext_vector_type(4)));

// ============ Kernel 1: fused params (blocks 0..511) + basis (512..1023) =======
// pa[row*257+k] = {lm, phase, cos(phase), sin(phase)}
// pb[row*257+k] = {start*w_k, mag}
// basis chunked layout: element (k, col) at ((k>>5)*4 + ((k>>3)&3))*512*8 + col*8 + (k&7)
__global__ __launch_bounds__(256) void k_prep(const float* __restrict__ sel,
                                              const float* __restrict__ items,
                                              float4* __restrict__ pa,
                                              float2* __restrict__ pb,
                                              _Float16* __restrict__ Bt) {
    int bid = blockIdx.x;
    int tid = threadIdx.x;
    if (bid < N_ROWS) {
        // ---- params: 1 row per block (proven-fast R3 shape) ----
        int row = bid;
        __shared__ float s[512];
        float v0 = sel[row * 512 + tid];
        float v1 = sel[row * 512 + tid + 256];
        s[tid]       = v0 > 0.f ? v0 : 0.f;
        s[tid + 256] = v1 > 0.f ? v1 : 0.f;
        __syncthreads();
        for (int k = tid; k < NBINS; k += 256) {
            float cm = 0.f, cp = 0.f, cs = 0.f;
            #pragma unroll 8
            for (int i = 0; i < 512; ++i) {
                float sv = s[i];
                const float* ip = items + i * N_COEFFS + k;
                cm = fmaf(sv, ip[0],   cm);
                cp = fmaf(sv, ip[257], cp);
                cs = fmaf(sv, ip[514], cs);
            }
            float sig_m = 1.f / (1.f + expf(-cm));
            float mag   = 0.5f + sig_m * 0.9999f * 0.5f;
            float lm    = logf(mag + 1e-12f);
            float ph    = tanhf(cp) * 3.14159265358979323846f;
            float sph, cph;
            sincosf(ph, &sph, &cph);
            float st = 1.f / (1.f + expf(-cs));
            float w  = (k == 0 || k == 256) ? (1.f / 512.f) : (2.f / 512.f);
            int idx = row * NBINS + k;
            pa[idx] = make_float4(lm, ph, cph, sph);
            pb[idx] = make_float2(st * w, mag);
        }
    } else {
        // ---- basis: permuted col jg -> sample n; chunked fp16 layout ----
        int jg = bid - N_ROWS;
        int n  = ((jg >> 7) << 6) + (jg & 63) + (((jg >> 6) & 1) << 8);
        for (int k = tid; k < KDIM; k += 256) {
            float v = 0.f;
            if (k < NBINS) {
                int r = (k * n) & 511;
                v = cosf(TWO_PI * (float)r * (1.f / 512.f));
            } else if (k < 2 * NBINS) {
                int r = ((k - NBINS) * n) & 511;
                v = -sinf(TWO_PI * (float)r * (1.f / 512.f));
            }
            size_t pos = ((size_t)((k >> 5) * 4 + ((k >> 3) & 3)) * 512 + jg) * 8 + (k & 7);
            Bt[pos] = (_Float16)v;
        }
    }
}

// ============ Kernel 2: fused A-gen(LDS) + MFMA + OLA + norm + scale ===========
// One block per row, 512 threads (8 waves = 2 wm x 4 wn), waves own 64f x 128c.
__global__ __launch_bounds__(512, 2) void k_row(const float4* __restrict__ pa,
                                                const float2* __restrict__ pb,
                                                const _Float16* __restrict__ basis,
                                                float* __restrict__ out) {
    __shared__ _Float16 Asm[PCH * 4096];     // 73728 B: 9 chunks x [f][32 swizzled]
    __shared__ _Float16 Bsm[2][16384];       // 65536 B: 2 x 4 planes x 512 cols x 8
    __shared__ float    SBB[4][64];
    __shared__ float    red[8];

    const int row  = blockIdx.x;
    const int t    = threadIdx.x;
    const int lane = t & 63;
    const int w    = t >> 6;
    const int wm   = w >> 2;            // frame-half 0..1 (64 frames each)
    const int wn   = w & 3;             // col-group 0..3 (128 permuted cols each)
    const int quad = lane >> 4;
    const int l16  = lane & 15;

    // ---------- A generation into LDS for one K-phase ----------
    auto agen = [&](int ph) {
        if (t < PCOLS) {
            int gc = ph * PCOLS + t;
            int bin; bool isCos;
            if (gc < NBINS)          { bin = gc;          isCos = true;  }
            else if (gc < 2 * NBINS) { bin = gc - NBINS;  isCos = false; }
            else                     { bin = 0;           isCos = true;  }
            float4 P = pa[row * NBINS + bin];
            float2 Q = pb[row * NBINS + bin];
            float D = 512.f * Q.x * Q.y;
            if (gc >= 2 * NBINS) D = 0.f;
            float c = P.z, s = P.w;
            int ch = t >> 5, g = (t >> 3) & 3, o = t & 7;
            _Float16* base = &Asm[ch * 4096 + o];
            for (int f = 0; f < N_FRAMES; ++f) {
                float val = isCos ? D * c : D * s;
                base[f * 32 + ((g ^ ((f >> 1) & 3) ^ ((f >> 3) & 3)) << 3)] = (_Float16)val;
                D *= Q.y;
                float nc = fmaf(c, P.z, -s * P.w);
                float ns = fmaf(s, P.z,  c * P.w);
                c = nc; s = ns;
            }
        }
    };

    // ---------- prologue: load chunk0 -> regs, A-gen(0), stage, load chunk1 ----
    half8 L[4];
    #pragma unroll
    for (int g = 0; g < 4; ++g)
        L[g] = *(const half8*)(basis + ((size_t)(0 * 4 + g) * 512 + t) * 8);
    agen(0);
    #pragma unroll
    for (int g = 0; g < 4; ++g)
        *(half8*)&Bsm[0][g * 4096 + t * 8] = L[g];
    #pragma unroll
    for (int g = 0; g < 4; ++g)
        L[g] = *(const half8*)(basis + ((size_t)(1 * 4 + g) * 512 + t) * 8);
    __syncthreads();

    // ---------- main K loop: 2 phases x 9 chunks, 1 barrier/iter ----------
    floatx4 acc[4][8] = {};   // [mt][nt]
    int p = 0;
    for (int ph = 0; ph < 2; ++ph) {
        if (ph == 1) { agen(1); __syncthreads(); }
        for (int ks = 0; ks < PCH; ++ks) {
            int gc = ph * PCH + ks;
            if (gc < NCHUNK - 1) {
                #pragma unroll
                for (int g = 0; g < 4; ++g)
                    *(half8*)&Bsm[p ^ 1][g * 4096 + t * 8] = L[g];
                if (gc < NCHUNK - 2) {
                    #pragma unroll
                    for (int g = 0; g < 4; ++g)
                        L[g] = *(const half8*)(basis + ((size_t)((gc + 2) * 4 + g) * 512 + t) * 8);
                }
            }
            half8 av[4];
            #pragma unroll
            for (int mt = 0; mt < 4; ++mt) {
                int m = wm * 64 + mt * 16 + l16;
                av[mt] = *(const half8*)&Asm[ks * 4096 + m * 32 +
                          ((quad ^ ((m >> 1) & 3) ^ ((m >> 3) & 3)) << 3)];
            }
            #pragma unroll
            for (int nt = 0; nt < 8; ++nt) {
                int u = wn * 128 + nt * 16 + l16;
                half8 bv = *(const half8*)&Bsm[p][quad * 4096 + u * 8];
                #pragma unroll
                for (int mt = 0; mt < 4; ++mt)
                    acc[mt][nt] = __builtin_amdgcn_mfma_f32_16x16x32_f16(av[mt], bv, acc[mt][nt], 0, 0, 0);
            }
            __syncthreads();
            p ^= 1;
        }
    }

    // ---------- epilogue: Hann + OLA in registers ----------
    float h1[4], h2[4];
    #pragma unroll
    for (int nt = 0; nt < 4; ++nt) {
        int n1 = wn * 64 + nt * 16 + l16;
        h1[nt] = 0.5f - 0.5f * cosf(TWO_PI * (float)n1 / 511.f);
        h2[nt] = 0.5f - 0.5f * cosf(TWO_PI * (float)(n1 + 256) / 511.f);
    }
    // pass frame-63 windowed second halves (wm0, mt3, quad3, rr3) to wm1 waves
    if (wm == 0 && quad == 3) {
        #pragma unroll
        for (int nt = 0; nt < 4; ++nt)
            SBB[wn][nt * 16 + l16] = acc[3][nt + 4][3] * h2[nt];
    }
    __syncthreads();

    float oreg[4][4][4];      // [mt][nt][rr]
    float prevLast[4] = {0.f, 0.f, 0.f, 0.f};
    float ssq = 0.f;
    #pragma unroll
    for (int mt = 0; mt < 4; ++mt) {
        #pragma unroll
        for (int nt = 0; nt < 4; ++nt) {
            float W2[4];
            #pragma unroll
            for (int rr = 0; rr < 4; ++rr) W2[rr] = acc[mt][nt + 4][rr] * h2[nt];
            float tmp = (quad == 3) ? prevLast[nt] : W2[3];
            float carry = __shfl(tmp, (lane + 48) & 63, 64);   // from lane-16
            if (mt == 0 && quad == 0)
                carry = (wm == 1) ? SBB[wn][nt * 16 + l16] : 0.f;
            float v = fmaf(acc[mt][nt][0], h1[nt], carry);
            oreg[mt][nt][0] = v; ssq = fmaf(v, v, ssq);
            #pragma unroll
            for (int rr = 1; rr < 4; ++rr) {
                v = fmaf(acc[mt][nt][rr], h1[nt], W2[rr - 1]);
                oreg[mt][nt][rr] = v; ssq = fmaf(v, v, ssq);
            }
            prevLast[nt] = W2[3];
        }
    }

    // ---------- block sum-of-squares, scale, store ----------
    #pragma unroll
    for (int off = 32; off > 0; off >>= 1) ssq += __shfl_down(ssq, off, 64);
    if (lane == 0) red[w] = ssq;
    __syncthreads();
    float tot = red[0] + red[1] + red[2] + red[3] + red[4] + red[5] + red[6] + red[7];
    float scale = 1.f / (sqrtf(tot) + 1e-8f);

    float* orow = out + (size_t)row * N_SAMP;
    #pragma unroll
    for (int mt = 0; mt < 4; ++mt) {
        #pragma unroll
        for (int nt = 0; nt < 4; ++nt) {
            int n1 = wn * 64 + nt * 16 + l16;
            #pragma unroll
            for (int rr = 0; rr < 4; ++rr) {
                int f = wm * 64 + mt * 16 + quad * 4 + rr;
                orow[f * 256 + n1] = oreg[mt][nt][rr] * scale;
            }
        }
    }
}

extern "C" void kernel_launch(void* const* d_in, const int* in_sizes, int n_in,
                              void* d_out, int out_size, void* d_ws, size_t ws_size,
                              hipStream_t stream) {
    const float* sel   = (const float*)d_in[0];   // (8,16,4,512)
    const float* items = (const float*)d_in[1];   // (512,771)
    float* out = (float*)d_out;                   // (512, 32768)

    char* ws = (char*)d_ws;
    size_t off = 0;
    float4* pa   = (float4*)(ws + off); off += (size_t)N_ROWS * NBINS * 16;   off = (off + 255) & ~255ull;
    float2* pb   = (float2*)(ws + off); off += (size_t)N_ROWS * NBINS * 8;    off = (off + 255) & ~255ull;
    _Float16* basis = (_Float16*)(ws + off);      // 18*4*512*8*2 B = 589824 B

    k_prep<<<dim3(N_ROWS + 512), dim3(256), 0, stream>>>(sel, items, pa, pb, basis);
    k_row<<<dim3(N_ROWS), dim3(512), 0, stream>>>(pa, pb, basis, out);
}